// Round 10
// baseline (403.856 us; speedup 1.0000x reference)
//
#include <hip/hip_runtime.h>

#define HID 30
#define TS  512
#define NB  16
#define LOG2E 1.44269504088896340736f
#define XPAD 17      // floats per t-row of xs   (odd stride: conflict-free)
#define HPADS 40     // shorts per col-row of h buffers

typedef __attribute__((ext_vector_type(8))) short bf16x8;
typedef __attribute__((ext_vector_type(4))) short s16x4;
typedef __attribute__((ext_vector_type(4))) float f32x4;

__device__ __forceinline__ float rcp_f(float x){ return __builtin_amdgcn_rcpf(x); }
__device__ __forceinline__ float ex2_f(float x){ return __builtin_amdgcn_exp2f(x); }

// Partner-half exchange (lane ^ 32): compiler-owned, guaranteed semantics.
__device__ __forceinline__ float xhalf(float v){
    return __shfl_xor(v, 32, 64);
}

__global__ __launch_bounds__(256, 2)
void lstm_mfma4(const float* __restrict__ batch,
                const float* __restrict__ W_ih,
                const float* __restrict__ W_hh,
                const float* __restrict__ b_ih,
                const float* __restrict__ b_hh,
                const float* __restrict__ W_fc,
                const float* __restrict__ b_fc,
                float* __restrict__ out)
{
    __shared__ float xs[TS * XPAD];                       // 34.8 KB
    __shared__ __align__(16) short hbhi[2][NB][HPADS];    // 2.5 KB
    __shared__ __align__(16) short hblo[2][NB][HPADS];    // 2.5 KB

    const int tid  = threadIdx.x;
    const int w    = tid >> 6;        // wave id: unit group 8w..8w+7
    const int lane = tid & 63;
    const int q    = lane >> 4;       // k-group / row-quadrant
    const int col  = lane & 15;       // batch col (and A-row index)
    const int b0   = blockIdx.x * NB;
    const bool half0 = (q < 2);

    // ---- stage x ----
    for (int i = 0; i < 32; ++i) {
        const int flat = i * 256 + tid;
        const int e = flat >> 9, tt = flat & 511;
        xs[tt * XPAD + e] = batch[(size_t)(b0 + e) * TS + tt];
    }
    // ---- zero h buffers (h(0) = 0)
    for (int i = tid; i < 2 * NB * HPADS; i += 256) {
        ((short*)hbhi)[i] = 0;
        ((short*)hblo)[i] = 0;
    }

    // ---- A fragments: wave w, tile m, row r=col: gate G=2m+(r>>3),
    //      unit u=8w+(r&7); k=q*8+jj; k<30:W_hh, 30:bias, 31:W_ih; prescaled.
    bf16x8 ahi0, alo0, ahi1, alo1;
    #pragma unroll
    for (int m = 0; m < 2; ++m) {
        const int G = 2 * m + (col >> 3);
        const int u = 8 * w + (col & 7);
        const float sG = (G == 2) ? (-2.0f * LOG2E) : (-LOG2E);
        const int R = G * HID + u;
        #pragma unroll
        for (int jj = 0; jj < 8; ++jj) {
            const int kk = q * 8 + jj;
            float wv = 0.0f;
            if (u < HID) {
                if (kk < HID)      wv = W_hh[R * HID + kk];
                else if (kk == 30) wv = b_ih[R] + b_hh[R];
                else               wv = W_ih[R];
            }
            wv *= sG;
            const __bf16 hi = (__bf16)wv;
            const __bf16 lo = (__bf16)(wv - (float)hi);
            const short hb = (short)__builtin_bit_cast(unsigned short, hi);
            const short lb = (short)__builtin_bit_cast(unsigned short, lo);
            if (m == 0) { ahi0[jj] = hb; alo0[jj] = lb; }
            else        { ahi1[jj] = hb; alo1[jj] = lb; }
        }
    }

    __syncthreads();

    const float TWOL = 2.0f * LOG2E;
    float cm[4] = {0.0f, 0.0f, 0.0f, 0.0f};   // -2L * c for 4 owned units

#define STEP(T, RB, WB)                                                        \
{                                                                              \
    bf16x8 bhi = *(const bf16x8*)&hbhi[RB][col][8 * q];                        \
    bf16x8 blo = *(const bf16x8*)&hblo[RB][col][8 * q];                        \
    const float xv = xs[(T) * XPAD + col];                                     \
    {                                                                          \
        const __bf16 xh = (__bf16)xv;                                          \
        const __bf16 xl = (__bf16)(xv - (float)xh);                            \
        const bool top = (q == 3);                                             \
        bhi[6] = top ? (short)0x3F80 : bhi[6];                                 \
        blo[6] = top ? (short)0      : blo[6];                                 \
        bhi[7] = top ? (short)__builtin_bit_cast(unsigned short, xh) : bhi[7]; \
        blo[7] = top ? (short)__builtin_bit_cast(unsigned short, xl) : blo[7]; \
    }                                                                          \
    f32x4 a0 = {0.f,0.f,0.f,0.f}, a1 = {0.f,0.f,0.f,0.f};                      \
    a0 = __builtin_amdgcn_mfma_f32_16x16x32_bf16(alo0, blo, a0, 0, 0, 0);      \
    a0 = __builtin_amdgcn_mfma_f32_16x16x32_bf16(alo0, bhi, a0, 0, 0, 0);      \
    a0 = __builtin_amdgcn_mfma_f32_16x16x32_bf16(ahi0, blo, a0, 0, 0, 0);      \
    a0 = __builtin_amdgcn_mfma_f32_16x16x32_bf16(ahi0, bhi, a0, 0, 0, 0);      \
    a1 = __builtin_amdgcn_mfma_f32_16x16x32_bf16(alo1, blo, a1, 0, 0, 0);      \
    a1 = __builtin_amdgcn_mfma_f32_16x16x32_bf16(alo1, bhi, a1, 0, 0, 0);      \
    a1 = __builtin_amdgcn_mfma_f32_16x16x32_bf16(ahi1, blo, a1, 0, 0, 0);      \
    a1 = __builtin_amdgcn_mfma_f32_16x16x32_bf16(ahi1, bhi, a1, 0, 0, 0);      \
    f32x4 hnew;                                                                \
    _Pragma("unroll")                                                          \
    for (int j = 0; j < 4; ++j) {                                              \
        const float o0 = xhalf(a0[j]);                                         \
        const float o1 = xhalf(a1[j]);                                         \
        const float ai = half0 ? a0[j] : o0;     /* i preact (-L scaled)  */   \
        const float af = half0 ? o0 : a0[j];     /* f preact (-L scaled)  */   \
        const float ag = half0 ? a1[j] : o1;     /* g preact (-2L scaled) */   \
        const float ao = half0 ? o1 : a1[j];     /* o preact (-L scaled)  */   \
        const float ei = ex2_f(ai), eg = ex2_f(ag);                            \
        const float rr = rcp_f((1.0f + ei) * (1.0f + eg));                     \
        const float igm = TWOL * ((eg - 1.0f) * rr);   /* -2L * i*g */         \
        const float fv = rcp_f(1.0f + ex2_f(af));                              \
        cm[j] = fmaf(fv, cm[j], igm);                                          \
        const float e = ex2_f(cm[j]), eo = ex2_f(ao);                          \
        const float r2 = rcp_f((1.0f + e) * (1.0f + eo));                      \
        hnew[j] = (1.0f - e) * r2;                    /* o * tanh(c) */        \
    }                                                                          \
    if (half0) {                                                               \
        s16x4 ph, pl;                                                          \
        _Pragma("unroll")                                                      \
        for (int j = 0; j < 4; ++j) {                                          \
            const __bf16 hh = (__bf16)hnew[j];                                 \
            const __bf16 hl = (__bf16)(hnew[j] - (float)hh);                   \
            ph[j] = (short)__builtin_bit_cast(unsigned short, hh);             \
            pl[j] = (short)__builtin_bit_cast(unsigned short, hl);             \
        }                                                                      \
        *(s16x4*)&hbhi[WB][col][8 * w + 4 * q] = ph;                           \
        *(s16x4*)&hblo[WB][col][8 * w + 4 * q] = pl;                           \
    }                                                                          \
    __syncthreads();                                                           \
}

    for (int t2 = 0; t2 < TS / 2; ++t2) {
        STEP(2 * t2,     0, 1)
        STEP(2 * t2 + 1, 1, 0)
    }
#undef STEP

    // ---- final projection: h(T) in buffer 0, reconstructed hi+lo ----
    if (tid < NB) {
        float acc = b_fc[0];
        #pragma unroll
        for (int u = 0; u < HID; ++u) {
            const __bf16 hh = __builtin_bit_cast(__bf16, (unsigned short)hbhi[0][tid][u]);
            const __bf16 hl = __builtin_bit_cast(__bf16, (unsigned short)hblo[0][tid][u]);
            acc = fmaf((float)hh + (float)hl, W_fc[u], acc);
        }
        out[b0 + tid] = acc;
    }
}

extern "C" void kernel_launch(void* const* d_in, const int* in_sizes, int n_in,
                              void* d_out, int out_size, void* d_ws, size_t ws_size,
                              hipStream_t stream) {
    const float* batch = (const float*)d_in[0];
    const float* W_ih  = (const float*)d_in[1];
    const float* W_hh  = (const float*)d_in[2];
    const float* b_ih  = (const float*)d_in[3];
    const float* b_hh  = (const float*)d_in[4];
    const float* W_fc  = (const float*)d_in[5];
    const float* b_fc  = (const float*)d_in[6];
    float* out = (float*)d_out;

    const int blocks = 8192 / NB;   // 512 blocks x 4 waves = 2048 waves
    lstm_mfma4<<<blocks, 256, 0, stream>>>(batch, W_ih, W_hh, b_ih, b_hh,
                                           W_fc, b_fc, out);
}